// Round 2
// baseline (3813.514 us; speedup 1.0000x reference)
//
#include <hip/hip_runtime.h>

typedef __bf16 bf16;
typedef __bf16 bf16x8 __attribute__((ext_vector_type(8)));
typedef float f32x4 __attribute__((ext_vector_type(4)));

__device__ __forceinline__ f32x4 mfma16(bf16x8 a, bf16x8 b, f32x4 c) {
  return __builtin_amdgcn_mfma_f32_16x16x32_bf16(a, b, c, 0, 0, 0);
}
__device__ __forceinline__ float sigm(float x) { return 1.0f / (1.0f + __expf(-x)); }
__device__ __forceinline__ float tanh_f(float x) {
  float e = __expf(-2.0f * fabsf(x));
  return copysignf((1.0f - e) / (1.0f + e), x);
}
__device__ __forceinline__ float ldin(const void* p, long i, int f32m) {
  return f32m ? ((const float*)p)[i] : (float)((const bf16*)p)[i];
}

// ---------------- dtype detection: even 16-bit words of N(0,1) data ----------------
// bf16 storage: words are real bf16 values, exponent <= ~0x82. f32 storage: even
// words are mantissa-low halves with random exponent bits -> ~25% have exp>=0xC0.
__global__ void detect_dtype(const unsigned short* __restrict__ p, int* __restrict__ flag) {
  __shared__ int cnt;
  if (threadIdx.x == 0) cnt = 0;
  __syncthreads();
  int c = 0;
  for (int i = threadIdx.x; i < 4096; i += 256) {
    unsigned e = (p[2 * i] >> 7) & 0xFFu;
    if (e >= 0xC0u) ++c;
  }
  atomicAdd(&cnt, c);
  __syncthreads();
  if (threadIdx.x == 0) *flag = (cnt > 64) ? 1 : 0;
}

// ---------------- converters ----------------
// hiAll/loAll element offsets:
//   wpad (padded tri Wih): 0 (tables below)       total 245760
//   tri Whh: 245760 + md*16384                    total 98304
//   r_Wih:  344064 + c*65536   r_Whh: 606208 + c*65536
//   dWihF: 868352  dWhhF: 933888  dWihB: 999424  dWhhB: 1064960   end 1130496
// fmisc float offsets:
//   tri bias: md*256 (0..1535)  r_b:1536  d_b_f:3584  d_b_b:4096
//   uscW: 4608 + mk*16384 (mk 0..11)  fc1W:201216 fc1b:209408 fc2W:209472 fc2b:209536

struct PadArgs { const void* src[6]; };
__global__ void conv_pad(PadArgs a, bf16* __restrict__ hi, bf16* __restrict__ lo,
                         const int* __restrict__ flag) {
  const int dinT[6] = {300, 300, 74, 74, 35, 35};
  const int kpT[6] = {320, 320, 96, 96, 64, 64};
  const int offT[6] = {0, 81920, 163840, 188416, 212992, 229376};
  int id = blockIdx.y;
  int din = dinT[id], kp = kpT[id];
  const void* s = a.src[id];
  bf16* h = hi + offT[id];
  bf16* l = lo + offT[id];
  int f32m = *flag;
  int total = 256 * kp;
  for (int i = blockIdx.x * blockDim.x + threadIdx.x; i < total; i += gridDim.x * blockDim.x) {
    int n = i / kp, k = i - n * kp;
    float v = (k < din) ? ldin(s, n * din + k, f32m) : 0.0f;
    bf16 hh = (bf16)v;
    h[i] = hh;
    l[i] = (bf16)(v - (float)hh);
  }
}

struct HiloArgs { const void* src[12]; int n[12]; int off[12]; };
__global__ void conv_hilo(HiloArgs a, bf16* __restrict__ hi, bf16* __restrict__ lo,
                          const int* __restrict__ flag) {
  int j = blockIdx.y;
  int n = a.n[j];
  const void* s = a.src[j];
  bf16* h = hi + a.off[j];
  bf16* l = lo + a.off[j];
  int f32m = *flag;
  for (int i = blockIdx.x * blockDim.x + threadIdx.x; i < n; i += gridDim.x * blockDim.x) {
    float v = ldin(s, i, f32m);
    bf16 hh = (bf16)v;
    h[i] = hh;
    l[i] = (bf16)(v - (float)hh);
  }
}

struct F32Args { const void* src[16]; int n[16]; int off[16]; };
__global__ void conv_f32(F32Args a, float* __restrict__ dst, const int* __restrict__ flag) {
  int j = blockIdx.y;
  int n = a.n[j];
  const void* s = a.src[j];
  float* d = dst + a.off[j];
  int f32m = *flag;
  for (int i = blockIdx.x * blockDim.x + threadIdx.x; i < n; i += gridDim.x * blockDim.x)
    d[i] = ldin(s, i, f32m);
}

// ---------------- fused trimodal bidirectional LSTMs ----------------
struct TriArgs {
  const void* x[3];
  const bf16* hiAll; const bf16* loAll;
  const float* fmisc;
  float* ctx;            // [3][1024][128] (cols 0..63 fwd, 64..127 bwd)
  const int* flag;
};

template <int DIN, int KP>
__device__ __forceinline__ void tri_body(const TriArgs& A, int md, int m, int d, int b0,
    bf16 (*Xhi)[328], bf16 (*Xlo)[328], float (*gs)[260], bf16 (*hhi)[72], bf16 (*hlo)[72]) {
  const int wpOffT[6] = {0, 81920, 163840, 188416, 212992, 229376};
  const bf16* wpH = A.hiAll + wpOffT[md];
  const bf16* wpL = A.loAll + wpOffT[md];
  const bf16* whhH = A.hiAll + 245760 + md * 16384;
  const bf16* whhL = A.loAll + 245760 + md * 16384;
  const float* bias = A.fmisc + md * 256;
  const void* xsrc = A.x[m];
  const int f32m = *A.flag;
  const int tid = threadIdx.x;
  const int lane = tid & 63, n16 = lane & 15, q = lane >> 4, w = tid >> 6;
  const int u = tid & 63, rg = tid >> 6;
  constexpr int NKS = KP / 32;

  // Whh^T B-fragments (hi/lo), constant over time
  bf16x8 wfh[4][2], wfl[4][2];
  for (int ct = 0; ct < 4; ++ct)
    for (int ks = 0; ks < 2; ++ks) {
      int o = (w * 64 + ct * 16 + n16) * 64 + ks * 32 + q * 8;
      wfh[ct][ks] = *(const bf16x8*)(whhH + o);
      wfl[ct][ks] = *(const bf16x8*)(whhL + o);
    }
  float bi = bias[u], bff = bias[64 + u], bgg = bias[128 + u], bo = bias[192 + u];

  for (int i = tid; i < 16 * 72; i += 256) { (&hhi[0][0])[i] = (bf16)0.0f; (&hlo[0][0])[i] = (bf16)0.0f; }
  float c4[4] = {0.f, 0.f, 0.f, 0.f};
  __syncthreads();

  for (int tg = 0; tg < 64; ++tg) {
    // stage 2 timesteps x 16 batch rows, hi/lo split, zero-padded K
    for (int idx = tid; idx < 32 * KP; idx += 256) {
      int r = idx / KP, k = idx - r * KP;
      int tl = r >> 4, bb = r & 15;
      int t = tg * 2 + tl; if (d) t = 127 - t;
      float v = 0.0f;
      if (k < DIN) v = ldin(xsrc, ((long)(b0 + bb) * 128 + t) * DIN + k, f32m);
      bf16 hh = (bf16)v;
      Xhi[r][k] = hh;
      Xlo[r][k] = (bf16)(v - (float)hh);
    }
    __syncthreads();

    f32x4 acc[2][4];
    const f32x4 zf = {0.f, 0.f, 0.f, 0.f};
    for (int rt = 0; rt < 2; ++rt) for (int ct = 0; ct < 4; ++ct) acc[rt][ct] = zf;
    for (int ks = 0; ks < NKS; ++ks) {
      bf16x8 ah0 = *(const bf16x8*)(&Xhi[n16][ks * 32 + q * 8]);
      bf16x8 ah1 = *(const bf16x8*)(&Xhi[16 + n16][ks * 32 + q * 8]);
      bf16x8 al0, al1;
      if (f32m) {
        al0 = *(const bf16x8*)(&Xlo[n16][ks * 32 + q * 8]);
        al1 = *(const bf16x8*)(&Xlo[16 + n16][ks * 32 + q * 8]);
      }
      for (int ct = 0; ct < 4; ++ct) {
        int o = (w * 64 + ct * 16 + n16) * KP + ks * 32 + q * 8;
        bf16x8 bh = *(const bf16x8*)(wpH + o);
        acc[0][ct] = mfma16(ah0, bh, acc[0][ct]);
        acc[1][ct] = mfma16(ah1, bh, acc[1][ct]);
        if (f32m) {
          bf16x8 bl = *(const bf16x8*)(wpL + o);
          acc[0][ct] = mfma16(al0, bh, acc[0][ct]);
          acc[1][ct] = mfma16(al1, bh, acc[1][ct]);
          acc[0][ct] = mfma16(ah0, bl, acc[0][ct]);
          acc[1][ct] = mfma16(ah1, bl, acc[1][ct]);
        }
      }
    }

    for (int tl = 0; tl < 2; ++tl) {
      for (int ks = 0; ks < 2; ++ks) {
        bf16x8 ah = *(const bf16x8*)(&hhi[n16][ks * 32 + q * 8]);
        bf16x8 al = *(const bf16x8*)(&hlo[n16][ks * 32 + q * 8]);
        for (int ct = 0; ct < 4; ++ct) {
          acc[tl][ct] = mfma16(ah, wfh[ct][ks], acc[tl][ct]);
          acc[tl][ct] = mfma16(al, wfh[ct][ks], acc[tl][ct]);
          if (f32m) acc[tl][ct] = mfma16(ah, wfl[ct][ks], acc[tl][ct]);
        }
      }
      for (int ct = 0; ct < 4; ++ct)
        for (int e = 0; e < 4; ++e)
          gs[q * 4 + e][w * 64 + ct * 16 + n16] = acc[tl][ct][e];
      __syncthreads();
      const bool lastStep = (tg == 63) && (tl == 1);
      for (int rr = 0; rr < 4; ++rr) {
        int row = rg * 4 + rr;
        float gi = gs[row][u] + bi;
        float gf = gs[row][64 + u] + bff;
        float gg = gs[row][128 + u] + bgg;
        float go = gs[row][192 + u] + bo;
        float c = sigm(gf) * c4[rr] + sigm(gi) * tanh_f(gg);
        c4[rr] = c;
        float h = sigm(go) * tanh_f(c);
        bf16 hh = (bf16)h;
        hhi[row][u] = hh;
        hlo[row][u] = (bf16)(h - (float)hh);
        if (lastStep) A.ctx[(m * 1024 + b0 + row) * 128 + d * 64 + u] = h;
      }
      __syncthreads();
    }
  }
}

__global__ __launch_bounds__(256) void tri_lstm(TriArgs A) {
  __shared__ __align__(16) bf16 Xhi[32][328];
  __shared__ __align__(16) bf16 Xlo[32][328];
  __shared__ float gs[16][260];
  __shared__ __align__(16) bf16 hhi[16][72];
  __shared__ __align__(16) bf16 hlo[16][72];
  int md = blockIdx.y;
  int m = md >> 1, d = md & 1, b0 = blockIdx.x * 16;
  if (m == 0)      tri_body<300, 320>(A, md, m, d, b0, Xhi, Xlo, gs, hhi, hlo);
  else if (m == 1) tri_body<74, 96>(A, md, m, d, b0, Xhi, Xlo, gs, hhi, hlo);
  else             tri_body<35, 64>(A, md, m, d, b0, Xhi, Xlo, gs, hhi, hlo);
}

// ---------------- usc einsum ----------------
__global__ __launch_bounds__(128) void usc_kern(const float* __restrict__ ctx,
                                                const float* __restrict__ fmisc,
                                                float* __restrict__ usc) {
  int b = blockIdx.x;
  int mk = blockIdx.y, mod = mk >> 2;
  const float* W = fmisc + 4608 + mk * 16384;
  const float* crow = ctx + (mod * 1024 + b) * 128;
  int e = threadIdx.x;
  float acc = 0.f;
  for (int dd = 0; dd < 128; ++dd) acc += crow[dd] * W[dd * 128 + e];
  usc[(mk * 1024 + b) * 128 + e] = acc;
}

// ---------------- fused capsule routing ----------------
struct RouteArgs {
  const float* usc;
  const bf16* hiAll; const bf16* loAll;
  const float* fmisc;
  float* dc;
  const int* flag;
};

__global__ __launch_bounds__(512) void routing(RouteArgs A) {
  extern __shared__ char smem[];
  float (*gs)[516]     = (float (*)[516])(smem);             // 33024 B
  float (*bc)[16][128] = (float (*)[16][128])(smem + 33024); // 32768 B
  float (*dcs)[128]    = (float (*)[128])(smem + 65792);     // 8192 B
  float (*rcs)[16]     = (float (*)[16])(smem + 73984);      // 1024 B
  bf16 (*xhi)[136]     = (bf16 (*)[136])(smem + 75008);
  bf16 (*xlo)[136]     = (bf16 (*)[136])(smem + 79360);
  bf16 (*hhi)[136]     = (bf16 (*)[136])(smem + 83712);
  bf16 (*hlo)[136]     = (bf16 (*)[136])(smem + 88064);      // end 92416

  const int tid = threadIdx.x;
  const int lane = tid & 63, n16 = lane & 15, q = lane >> 4, w = tid >> 6;
  const int u = tid & 127, rg = tid >> 7;
  const int b0 = blockIdx.x * 16;
  const int f32m = *A.flag;

  if (tid < 256) rcs[tid >> 4][tid & 15] = 1.0f;
  __syncthreads();

  const int nsteps[6] = {2, 2, 2, 3, 7, 7};
  const int capoff[4] = {0, 2, 4, 6};
  const int WihOff[6] = {344064, 409600, 475136, 540672, 868352, 999424};
  const int WhhOff[6] = {606208, 671744, 737280, 802816, 933888, 1064960};
  const int bOff[6]   = {1536, 2048, 2560, 3072, 3584, 4096};

  for (int it = 0; it < 4; ++it) {
    if (tid < 16) {
      int row = tid;
      const int goff[5] = {0, 2, 4, 6, 9};
      const int gn[5] = {2, 2, 2, 3, 7};
      for (int g = 0; g < 5; ++g) {
        float mx = -1e30f;
        for (int j = 0; j < gn[g]; ++j) mx = fmaxf(mx, rcs[row][goff[g] + j]);
        float s = 0.f, ev[7];
        for (int j = 0; j < gn[g]; ++j) { ev[j] = __expf(rcs[row][goff[g] + j] - mx); s += ev[j]; }
        float inv = 1.0f / s;
        for (int j = 0; j < gn[g]; ++j) rcs[row][goff[g] + j] = ev[j] * inv;
      }
    }
    __syncthreads();

    for (int chain = 0; chain < 6; ++chain) {
      const bf16* WihH = A.hiAll + WihOff[chain];
      const bf16* WihL = A.loAll + WihOff[chain];
      const bf16* WhhH = A.hiAll + WhhOff[chain];
      const bf16* WhhL = A.loAll + WhhOff[chain];
      const float* bias = A.fmisc + bOff[chain];
      float bI = bias[u], bF = bias[128 + u], bG = bias[256 + u], bO = bias[384 + u];

      for (int i = tid; i < 16 * 136; i += 512) { (&hhi[0][0])[i] = (bf16)0.0f; (&hlo[0][0])[i] = (bf16)0.0f; }
      float creg[4] = {0.f, 0.f, 0.f, 0.f};
      __syncthreads();

      const int ns = nsteps[chain];
      for (int s = 0; s < ns; ++s) {
        int mk, rcIdx, bcIdx = -1;
        if (chain < 4) {
          rcIdx = capoff[chain] + s;
          const int preMk0[4] = {0, 1, 5, 2};
          const int preMk1[4] = {4, 8, 9, 6};
          mk = (s == 0) ? preMk0[chain] : (s == 1 ? preMk1[chain] : 10);
        } else {
          int j = (chain == 4) ? s : 6 - s;
          rcIdx = 9 + j;
          if (j < 3) { const int dmk[3] = {3, 7, 11}; mk = dmk[j]; }
          else { mk = -1; bcIdx = j - 3; }
        }
        for (int rr = 0; rr < 4; ++rr) {
          int row = rg * 4 + rr;
          float pv = (mk >= 0) ? A.usc[(mk * 1024 + b0 + row) * 128 + u] : bc[bcIdx][row][u];
          float xv = rcs[row][rcIdx] * pv;
          bf16 xh = (bf16)xv;
          xhi[row][u] = xh;
          xlo[row][u] = (bf16)(xv - (float)xh);
        }
        __syncthreads();

        f32x4 acc[4];
        const f32x4 zf = {0.f, 0.f, 0.f, 0.f};
        for (int ct = 0; ct < 4; ++ct) acc[ct] = zf;
        for (int ks = 0; ks < 4; ++ks) {
          bf16x8 axh = *(const bf16x8*)(&xhi[n16][ks * 32 + q * 8]);
          bf16x8 axl = *(const bf16x8*)(&xlo[n16][ks * 32 + q * 8]);
          for (int ct = 0; ct < 4; ++ct) {
            int o = (w * 64 + ct * 16 + n16) * 128 + ks * 32 + q * 8;
            bf16x8 bh = *(const bf16x8*)(WihH + o);
            acc[ct] = mfma16(axh, bh, acc[ct]);
            acc[ct] = mfma16(axl, bh, acc[ct]);
            if (f32m) {
              bf16x8 bl = *(const bf16x8*)(WihL + o);
              acc[ct] = mfma16(axh, bl, acc[ct]);
            }
          }
        }
        for (int ks = 0; ks < 4; ++ks) {
          bf16x8 ahh = *(const bf16x8*)(&hhi[n16][ks * 32 + q * 8]);
          bf16x8 ahl = *(const bf16x8*)(&hlo[n16][ks * 32 + q * 8]);
          for (int ct = 0; ct < 4; ++ct) {
            int o = (w * 64 + ct * 16 + n16) * 128 + ks * 32 + q * 8;
            bf16x8 bh = *(const bf16x8*)(WhhH + o);
            acc[ct] = mfma16(ahh, bh, acc[ct]);
            acc[ct] = mfma16(ahl, bh, acc[ct]);
            if (f32m) {
              bf16x8 bl = *(const bf16x8*)(WhhL + o);
              acc[ct] = mfma16(ahh, bl, acc[ct]);
            }
          }
        }
        for (int ct = 0; ct < 4; ++ct)
          for (int e = 0; e < 4; ++e)
            gs[q * 4 + e][w * 64 + ct * 16 + n16] = acc[ct][e];
        __syncthreads();

        const bool lastStep = (s == ns - 1);
        for (int rr = 0; rr < 4; ++rr) {
          int row = rg * 4 + rr;
          float gi = gs[row][u] + bI;
          float gf = gs[row][128 + u] + bF;
          float gg = gs[row][256 + u] + bG;
          float go = gs[row][384 + u] + bO;
          float c = sigm(gf) * creg[rr] + sigm(gi) * tanh_f(gg);
          creg[rr] = c;
          float h = sigm(go) * tanh_f(c);
          bf16 hh = (bf16)h;
          hhi[row][u] = hh;
          hlo[row][u] = (bf16)(h - (float)hh);
          if (lastStep) {
            if (chain < 4) bc[chain][row][u] = h;
            else if (chain == 4) dcs[row][u] = h;
            else dcs[row][u] += h;
          }
        }
        __syncthreads();
      }
    }

    if (it < 3) {
      if (tid < 256) {
        int row = tid >> 4, cap = tid & 15;
        const int preMkTab[9] = {0, 4, 1, 8, 5, 9, 2, 6, 10};
        float a = 0.f;
        if (cap < 9) {
          int i = (cap < 2) ? 0 : (cap < 4) ? 1 : (cap < 6) ? 2 : 3;
          const float* pr = A.usc + (preMkTab[cap] * 1024 + b0 + row) * 128;
          for (int dd = 0; dd < 128; ++dd) a += pr[dd] * bc[i][row][dd];
        } else {
          int j = cap - 9;
          if (j < 3) {
            const int dmk[3] = {3, 7, 11};
            const float* pr = A.usc + (dmk[j] * 1024 + b0 + row) * 128;
            for (int dd = 0; dd < 128; ++dd) a += pr[dd] * dcs[row][dd];
          } else {
            for (int dd = 0; dd < 128; ++dd) a += bc[j - 3][row][dd] * dcs[row][dd];
          }
        }
        rcs[row][cap] += a;
      }
      __syncthreads();
    }
  }

  for (int rr = 0; rr < 4; ++rr) {
    int row = rg * 4 + rr;
    A.dc[(b0 + row) * 128 + u] = dcs[row][u];
  }
}

// ---------------- head ----------------
__global__ __launch_bounds__(64) void head(const float* __restrict__ dc, const float* __restrict__ fcw,
                                           void* __restrict__ out, const int* __restrict__ flag) {
  int b = blockIdx.x, j = threadIdx.x;
  const float* r = dc + b * 128;
  float acc = fcw[209408 + j];
  for (int dd = 0; dd < 128; ++dd) acc += r[dd] * fcw[201216 + j * 128 + dd];
  float o = tanh_f(acc) * fcw[209472 + j];
  for (int off = 32; off; off >>= 1) o += __shfl_down(o, off, 64);
  if (j == 0) {
    float res = o + fcw[209536];
    if (*flag) ((float*)out)[b] = res;
    else ((bf16*)out)[b] = (bf16)res;
  }
}

extern "C" void kernel_launch(void* const* d_in, const int* in_sizes, int n_in,
                              void* d_out, int out_size, void* d_ws, size_t ws_size,
                              hipStream_t stream) {
  float* fw = (float*)d_ws;
  int* flag = (int*)d_ws;
  float* ctx = fw + 4;                 // 393216
  float* usc = ctx + 393216;           // 1572864
  float* dcw = usc + 1572864;          // 131072
  float* fmisc = dcw + 131072;         // 209552
  bf16* hiAll = (bf16*)(fmisc + 209552);  // 1130496 el
  bf16* loAll = hiAll + 1130496;

  hipLaunchKernelGGL(detect_dtype, dim3(1), dim3(256), 0, stream,
                     (const unsigned short*)d_in[0], flag);

  PadArgs pa;
  HiloArgs ha;
  for (int m = 0; m < 3; ++m)
    for (int dd = 0; dd < 2; ++dd) {
      int md = m * 2 + dd;
      pa.src[md] = d_in[3 + m * 6 + dd * 3 + 0];
      ha.src[md] = d_in[3 + m * 6 + dd * 3 + 1];
      ha.n[md] = 16384;
      ha.off[md] = 245760 + md * 16384;
    }
  const int hsrc[6] = {24, 25, 27, 28, 30, 31};
  const int hn[6] = {262144, 262144, 65536, 65536, 65536, 65536};
  const int hoff[6] = {344064, 606208, 868352, 933888, 999424, 1064960};
  for (int j = 0; j < 6; ++j) { ha.src[6 + j] = d_in[hsrc[j]]; ha.n[6 + j] = hn[j]; ha.off[6 + j] = hoff[j]; }
  hipLaunchKernelGGL(conv_pad, dim3(64, 6), dim3(256), 0, stream, pa, hiAll, loAll, (const int*)flag);
  hipLaunchKernelGGL(conv_hilo, dim3(128, 12), dim3(256), 0, stream, ha, hiAll, loAll, (const int*)flag);

  F32Args fa;
  for (int m = 0; m < 3; ++m)
    for (int dd = 0; dd < 2; ++dd) {
      int md = m * 2 + dd;
      fa.src[md] = d_in[3 + m * 6 + dd * 3 + 2];
      fa.n[md] = 256;
      fa.off[md] = md * 256;
    }
  const int fsrc[10] = {26, 29, 32, 21, 22, 23, 33, 34, 35, 36};
  const int fn[10] = {2048, 512, 512, 65536, 65536, 65536, 8192, 64, 64, 1};
  const int foff[10] = {1536, 3584, 4096, 4608, 70144, 135680, 201216, 209408, 209472, 209536};
  for (int j = 0; j < 10; ++j) { fa.src[6 + j] = d_in[fsrc[j]]; fa.n[6 + j] = fn[j]; fa.off[6 + j] = foff[j]; }
  hipLaunchKernelGGL(conv_f32, dim3(64, 16), dim3(256), 0, stream, fa, fmisc, (const int*)flag);

  TriArgs ta;
  ta.x[0] = d_in[0]; ta.x[1] = d_in[1]; ta.x[2] = d_in[2];
  ta.hiAll = hiAll; ta.loAll = loAll; ta.fmisc = fmisc; ta.ctx = ctx; ta.flag = flag;
  hipLaunchKernelGGL(tri_lstm, dim3(64, 6), dim3(256), 0, stream, ta);

  hipLaunchKernelGGL(usc_kern, dim3(1024, 12), dim3(128), 0, stream,
                     (const float*)ctx, (const float*)fmisc, usc);

  RouteArgs ra;
  ra.usc = usc; ra.hiAll = hiAll; ra.loAll = loAll; ra.fmisc = fmisc; ra.dc = dcw; ra.flag = flag;
  const int routeSmem = 92416;
  hipFuncSetAttribute((const void*)routing, hipFuncAttributeMaxDynamicSharedMemorySize, routeSmem);
  hipLaunchKernelGGL(routing, dim3(64), dim3(512), routeSmem, stream, ra);

  hipLaunchKernelGGL(head, dim3(1024), dim3(64), 0, stream,
                     (const float*)dcw, (const float*)fmisc, d_out, (const int*)flag);
}

// Round 3
// 1607.987 us; speedup vs baseline: 2.3716x; 2.3716x over previous
//
#include <hip/hip_runtime.h>

typedef __bf16 bf16;
typedef __bf16 bf16x8 __attribute__((ext_vector_type(8)));
typedef float f32x4 __attribute__((ext_vector_type(4)));

__device__ __forceinline__ f32x4 mfma16(bf16x8 a, bf16x8 b, f32x4 c) {
  return __builtin_amdgcn_mfma_f32_16x16x32_bf16(a, b, c, 0, 0, 0);
}
__device__ __forceinline__ float sigm(float x) { return 1.0f / (1.0f + __expf(-x)); }
__device__ __forceinline__ float tanh_f(float x) {
  float e = __expf(-2.0f * fabsf(x));
  return copysignf((1.0f - e) / (1.0f + e), x);
}
__device__ __forceinline__ float ldin(const void* p, long i, int f32m) {
  return f32m ? ((const float*)p)[i] : (float)((const bf16*)p)[i];
}
__device__ __forceinline__ unsigned short bfu(bf16 h) { return __builtin_bit_cast(unsigned short, h); }

// ---------------- dtype detection ----------------
__global__ void detect_dtype(const unsigned short* __restrict__ p, int* __restrict__ flag) {
  __shared__ int cnt;
  if (threadIdx.x == 0) cnt = 0;
  __syncthreads();
  int c = 0;
  for (int i = threadIdx.x; i < 4096; i += 256) {
    unsigned e = (p[2 * i] >> 7) & 0xFFu;
    if (e >= 0xC0u) ++c;
  }
  atomicAdd(&cnt, c);
  __syncthreads();
  if (threadIdx.x == 0) *flag = (cnt > 64) ? 1 : 0;
}

// ---------------- converters (layouts same as R2) ----------------
struct PadArgs { const void* src[6]; };
__global__ void conv_pad(PadArgs a, bf16* __restrict__ hi, bf16* __restrict__ lo,
                         const int* __restrict__ flag) {
  const int dinT[6] = {300, 300, 74, 74, 35, 35};
  const int kpT[6] = {320, 320, 96, 96, 64, 64};
  const int offT[6] = {0, 81920, 163840, 188416, 212992, 229376};
  int id = blockIdx.y;
  int din = dinT[id], kp = kpT[id];
  const void* s = a.src[id];
  bf16* h = hi + offT[id];
  bf16* l = lo + offT[id];
  int f32m = *flag;
  int total = 256 * kp;
  for (int i = blockIdx.x * blockDim.x + threadIdx.x; i < total; i += gridDim.x * blockDim.x) {
    int n = i / kp, k = i - n * kp;
    float v = (k < din) ? ldin(s, n * din + k, f32m) : 0.0f;
    bf16 hh = (bf16)v;
    h[i] = hh;
    l[i] = (bf16)(v - (float)hh);
  }
}

struct HiloArgs { const void* src[12]; int n[12]; int off[12]; };
__global__ void conv_hilo(HiloArgs a, bf16* __restrict__ hi, bf16* __restrict__ lo,
                          const int* __restrict__ flag) {
  int j = blockIdx.y;
  int n = a.n[j];
  const void* s = a.src[j];
  bf16* h = hi + a.off[j];
  bf16* l = lo + a.off[j];
  int f32m = *flag;
  for (int i = blockIdx.x * blockDim.x + threadIdx.x; i < n; i += gridDim.x * blockDim.x) {
    float v = ldin(s, i, f32m);
    bf16 hh = (bf16)v;
    h[i] = hh;
    l[i] = (bf16)(v - (float)hh);
  }
}

struct F32Args { const void* src[16]; int n[16]; int off[16]; };
__global__ void conv_f32(F32Args a, float* __restrict__ dst, const int* __restrict__ flag) {
  int j = blockIdx.y;
  int n = a.n[j];
  const void* s = a.src[j];
  float* d = dst + a.off[j];
  int f32m = *flag;
  for (int i = blockIdx.x * blockDim.x + threadIdx.x; i < n; i += gridDim.x * blockDim.x)
    d[i] = ldin(s, i, f32m);
}

__global__ void init_rc(float* __restrict__ rcs) {
  int i = blockIdx.x * 256 + threadIdx.x;
  if (i < 16384) rcs[i] = 1.0f;
}

// ---------------- fused trimodal bidirectional LSTMs ----------------
struct TriArgs {
  const void* x[3];
  const bf16* hiAll; const bf16* loAll;
  const float* fmisc;
  float* ctx;
  const int* flag;
};

// wave w owns gate-slice u = w*16 + n16; output tile for gate g: rows g*64+u.
template <int DIN, int KP, int CHUNK>
__device__ void tri_body(const void* __restrict__ xsrc,
                         const bf16* __restrict__ wpH, const bf16* __restrict__ wpL,
                         const bf16* __restrict__ whhH, const bf16* __restrict__ whhL,
                         const float* __restrict__ bias, float* __restrict__ ctx,
                         int m, int d, int b0, int f32m, char* sm) {
  constexpr int XP = KP + 8;
  constexpr int NKS = KP / 32;
  constexpr int NCH = DIN / CHUNK;
  constexpr int SLOTS = 32 * NCH;
  constexpr int NSLOT = (SLOTS + 255) / 256;

  bf16 (*Xhi)[XP] = (bf16 (*)[XP])sm;
  bf16 (*Xlo)[XP] = (bf16 (*)[XP])(sm + 32 * XP * 2);
  bf16 (*hhi)[16][72] = (bf16 (*)[16][72])(sm + 64 * XP * 2);
  bf16 (*hlo)[16][72] = (bf16 (*)[16][72])(sm + 64 * XP * 2 + 9216);

  const int tid = threadIdx.x;
  const int lane = tid & 63, n16 = lane & 15, q = lane >> 4, w = tid >> 6;
  const int u = w * 16 + n16;

  // zero LDS (X pads + h buffers)
  {
    unsigned* z = (unsigned*)sm;
    int nz = (64 * XP * 2 + 18432) >> 2;
    for (int i = tid; i < nz; i += 256) z[i] = 0u;
  }

  // Whh^T fragments (hi/lo) in registers
  bf16x8 wfh[4][2], wfl[4][2];
#pragma unroll
  for (int g = 0; g < 4; ++g)
#pragma unroll
    for (int ks = 0; ks < 2; ++ks) {
      int o = (g * 64 + u) * 64 + ks * 32 + q * 8;
      wfh[g][ks] = *(const bf16x8*)(whhH + o);
      wfl[g][ks] = *(const bf16x8*)(whhL + o);
    }
  float bg[4];
#pragma unroll
  for (int g = 0; g < 4; ++g) bg[g] = bias[g * 64 + u];

  uint4 pf[NSLOT];
  auto stage_load = [&](int tg) {
    int t0 = tg * 2;
#pragma unroll
    for (int i = 0; i < NSLOT; ++i) {
      int slot = tid + i * 256;
      if (slot < SLOTS) {
        int r = slot / NCH, c = slot - r * NCH;
        int tl = r >> 4, bb = r & 15;
        int t = t0 + tl; if (d) t = 127 - t;
        int base = ((b0 + bb) * 128 + t) * DIN + c * CHUNK;
        if (f32m) {
          const float* p = (const float*)xsrc + base;
          if constexpr (CHUNK == 4) pf[i] = *(const uint4*)p;
          else if constexpr (CHUNK == 2) { uint2 v = *(const uint2*)p; pf[i].x = v.x; pf[i].y = v.y; }
          else pf[i].x = *(const unsigned*)p;
        } else {
          const unsigned short* p = (const unsigned short*)xsrc + base;
          if constexpr (CHUNK == 4) { uint2 v = *(const uint2*)p; pf[i].x = v.x; pf[i].y = v.y; }
          else if constexpr (CHUNK == 2) pf[i].x = *(const unsigned*)p;
          else pf[i].x = *p;
        }
      }
    }
  };
  auto stage_store = [&]() {
#pragma unroll
    for (int i = 0; i < NSLOT; ++i) {
      int slot = tid + i * 256;
      if (slot < SLOTS) {
        int r = slot / NCH, c = slot - r * NCH;
        if (f32m) {
          float v[4];
          v[0] = __uint_as_float(pf[i].x); v[1] = __uint_as_float(pf[i].y);
          v[2] = __uint_as_float(pf[i].z); v[3] = __uint_as_float(pf[i].w);
          unsigned short hb[4], lb[4];
#pragma unroll
          for (int e = 0; e < CHUNK; ++e) {
            bf16 h = (bf16)v[e];
            hb[e] = bfu(h);
            lb[e] = bfu((bf16)(v[e] - (float)h));
          }
          if constexpr (CHUNK == 4) {
            uint2 H, L;
            H.x = hb[0] | ((unsigned)hb[1] << 16); H.y = hb[2] | ((unsigned)hb[3] << 16);
            L.x = lb[0] | ((unsigned)lb[1] << 16); L.y = lb[2] | ((unsigned)lb[3] << 16);
            *(uint2*)&Xhi[r][c * 4] = H;
            *(uint2*)&Xlo[r][c * 4] = L;
          } else if constexpr (CHUNK == 2) {
            *(unsigned*)&Xhi[r][c * 2] = hb[0] | ((unsigned)hb[1] << 16);
            *(unsigned*)&Xlo[r][c * 2] = lb[0] | ((unsigned)lb[1] << 16);
          } else {
            *(unsigned short*)&Xhi[r][c] = hb[0];
            *(unsigned short*)&Xlo[r][c] = lb[0];
          }
        } else {
          if constexpr (CHUNK == 4) { uint2 H; H.x = pf[i].x; H.y = pf[i].y; *(uint2*)&Xhi[r][c * 4] = H; }
          else if constexpr (CHUNK == 2) *(unsigned*)&Xhi[r][c * 2] = pf[i].x;
          else *(unsigned short*)&Xhi[r][c] = (unsigned short)pf[i].x;
        }
      }
    }
  };

  float c4[4] = {0.f, 0.f, 0.f, 0.f};
  int par = 0;
  stage_load(0);
  __syncthreads();  // zero-init visible

  for (int tg = 0; tg < 64; ++tg) {
    stage_store();
    if (tg < 63) stage_load(tg + 1);
    __syncthreads();

    f32x4 acc[2][4];
    const f32x4 zf = {0.f, 0.f, 0.f, 0.f};
#pragma unroll
    for (int rt = 0; rt < 2; ++rt)
#pragma unroll
      for (int g = 0; g < 4; ++g) acc[rt][g] = zf;

#pragma unroll
    for (int ks = 0; ks < NKS; ++ks) {
      bf16x8 ah0 = *(const bf16x8*)(&Xhi[n16][ks * 32 + q * 8]);
      bf16x8 ah1 = *(const bf16x8*)(&Xhi[16 + n16][ks * 32 + q * 8]);
      bf16x8 al0 = *(const bf16x8*)(&Xlo[n16][ks * 32 + q * 8]);
      bf16x8 al1 = *(const bf16x8*)(&Xlo[16 + n16][ks * 32 + q * 8]);
#pragma unroll
      for (int g = 0; g < 4; ++g) {
        int o = (g * 64 + u) * KP + ks * 32 + q * 8;
        bf16x8 bh = *(const bf16x8*)(wpH + o);
        bf16x8 bl = *(const bf16x8*)(wpL + o);
        acc[0][g] = mfma16(ah0, bh, acc[0][g]);
        acc[1][g] = mfma16(ah1, bh, acc[1][g]);
        acc[0][g] = mfma16(al0, bh, acc[0][g]);
        acc[1][g] = mfma16(al1, bh, acc[1][g]);
        acc[0][g] = mfma16(ah0, bl, acc[0][g]);
        acc[1][g] = mfma16(ah1, bl, acc[1][g]);
      }
    }

#pragma unroll
    for (int tl = 0; tl < 2; ++tl) {
#pragma unroll
      for (int ks = 0; ks < 2; ++ks) {
        bf16x8 ah = *(const bf16x8*)(&hhi[par][n16][ks * 32 + q * 8]);
        bf16x8 al = *(const bf16x8*)(&hlo[par][n16][ks * 32 + q * 8]);
#pragma unroll
        for (int g = 0; g < 4; ++g) {
          acc[tl][g] = mfma16(ah, wfh[g][ks], acc[tl][g]);
          acc[tl][g] = mfma16(al, wfh[g][ks], acc[tl][g]);
          acc[tl][g] = mfma16(ah, wfl[g][ks], acc[tl][g]);
        }
      }
      const bool lastStep = (tg == 63) && (tl == 1);
#pragma unroll
      for (int e = 0; e < 4; ++e) {
        int row = q * 4 + e;
        float gi = acc[tl][0][e] + bg[0];
        float gf = acc[tl][1][e] + bg[1];
        float gg = acc[tl][2][e] + bg[2];
        float go = acc[tl][3][e] + bg[3];
        float c = sigm(gf) * c4[e] + sigm(gi) * tanh_f(gg);
        c4[e] = c;
        float h = sigm(go) * tanh_f(c);
        bf16 hh = (bf16)h;
        hhi[par ^ 1][row][u] = hh;
        hlo[par ^ 1][row][u] = (bf16)(h - (float)hh);
        if (lastStep) ctx[(m * 1024 + b0 + row) * 128 + d * 64 + u] = h;
      }
      par ^= 1;
      __syncthreads();
    }
  }
}

__global__ __launch_bounds__(256) void tri_lstm(TriArgs A) {
  __shared__ __align__(16) char sm[64 * 328 * 2 + 18432];
  int bid = blockIdx.x;
  int md = bid >> 6, xb = bid & 63;
  int m = md >> 1, d = md & 1, b0 = xb * 16;
  const int wpOffT[6] = {0, 81920, 163840, 188416, 212992, 229376};
  const bf16* wpH = A.hiAll + wpOffT[md];
  const bf16* wpL = A.loAll + wpOffT[md];
  const bf16* whhH = A.hiAll + 245760 + md * 16384;
  const bf16* whhL = A.loAll + 245760 + md * 16384;
  const float* bias = A.fmisc + md * 256;
  int f32m = *A.flag;
  if (m == 0)      tri_body<300, 320, 4>(A.x[0], wpH, wpL, whhH, whhL, bias, A.ctx, m, d, b0, f32m, sm);
  else if (m == 1) tri_body<74, 96, 2>(A.x[1], wpH, wpL, whhH, whhL, bias, A.ctx, m, d, b0, f32m, sm);
  else             tri_body<35, 64, 1>(A.x[2], wpH, wpL, whhH, whhL, bias, A.ctx, m, d, b0, f32m, sm);
}

// ---------------- usc einsum (4 rows/block for W reuse) ----------------
__global__ __launch_bounds__(128) void usc_kern(const float* __restrict__ ctx,
                                                const float* __restrict__ fmisc,
                                                float* __restrict__ usc) {
  __shared__ float cr[4][128];
  int b0 = blockIdx.x * 4;
  int mk = blockIdx.y, mod = mk >> 2;
  int e = threadIdx.x;
  const float* W = fmisc + 4608 + mk * 16384;
  for (int i = e; i < 512; i += 128) {
    int r = i >> 7, dd = i & 127;
    cr[r][dd] = ctx[(mod * 1024 + b0 + r) * 128 + dd];
  }
  __syncthreads();
  float a0 = 0.f, a1 = 0.f, a2 = 0.f, a3 = 0.f;
  for (int dd = 0; dd < 128; ++dd) {
    float wv = W[dd * 128 + e];
    a0 += cr[0][dd] * wv; a1 += cr[1][dd] * wv;
    a2 += cr[2][dd] * wv; a3 += cr[3][dd] * wv;
  }
  usc[(mk * 1024 + b0 + 0) * 128 + e] = a0;
  usc[(mk * 1024 + b0 + 1) * 128 + e] = a1;
  usc[(mk * 1024 + b0 + 2) * 128 + e] = a2;
  usc[(mk * 1024 + b0 + 3) * 128 + e] = a3;
}

// ---------------- routing phase kernels ----------------
// Shared step layout: 512 thr, 8 waves; wave w owns u = w*16+n16; gate g tile rows g*128+u.
// Ping-pong x/h LDS buffers, 1 barrier per step.

#define LSTM_STEP_DECL \
  const int tid = threadIdx.x; \
  const int lane = tid & 63, n16 = lane & 15, q = lane >> 4, w = tid >> 6; \
  const int u = w * 16 + n16; \
  const int u2 = tid & 127, rgg = tid >> 7;

__device__ __forceinline__ void lstm_step_mfma(
    f32x4* acc, const bf16 (*xhi)[16][136], const bf16 (*xlo)[16][136],
    const bf16 (*hhi)[16][136], const bf16 (*hlo)[16][136], int p,
    const bf16* __restrict__ WihH, const bf16* __restrict__ WihL,
    const bf16x8 (*whf)[4], const bf16x8 (*whl)[4],
    int n16, int q, int u) {
#pragma unroll
  for (int ks = 0; ks < 4; ++ks) {
    bf16x8 axh = *(const bf16x8*)(&xhi[p][n16][ks * 32 + q * 8]);
    bf16x8 axl = *(const bf16x8*)(&xlo[p][n16][ks * 32 + q * 8]);
    bf16x8 ahh = *(const bf16x8*)(&hhi[p][n16][ks * 32 + q * 8]);
    bf16x8 ahl = *(const bf16x8*)(&hlo[p][n16][ks * 32 + q * 8]);
#pragma unroll
    for (int g = 0; g < 4; ++g) {
      int o = (g * 128 + u) * 128 + ks * 32 + q * 8;
      bf16x8 bh = *(const bf16x8*)(WihH + o);
      bf16x8 bl = *(const bf16x8*)(WihL + o);
      acc[g] = mfma16(axh, bh, acc[g]);
      acc[g] = mfma16(axl, bh, acc[g]);
      acc[g] = mfma16(axh, bl, acc[g]);
      acc[g] = mfma16(ahh, whf[g][ks], acc[g]);
      acc[g] = mfma16(ahl, whf[g][ks], acc[g]);
      acc[g] = mfma16(ahh, whl[g][ks], acc[g]);
    }
  }
}

__global__ __launch_bounds__(512) void rchain(const float* __restrict__ usc,
                                              const float* __restrict__ rcs,
                                              const bf16* __restrict__ hiAll,
                                              const bf16* __restrict__ loAll,
                                              const float* __restrict__ fmisc,
                                              float* __restrict__ bcg) {
  __shared__ __align__(16) bf16 xhi[2][16][136], xlo[2][16][136], hhi[2][16][136], hlo[2][16][136];
  __shared__ float rcl[16][3];
  LSTM_STEP_DECL
  const int chain = blockIdx.y;
  const int b0 = blockIdx.x * 16;
  const int WihOff[4] = {344064, 409600, 475136, 540672};
  const int WhhOff[4] = {606208, 671744, 737280, 802816};
  const int bOff[4] = {1536, 2048, 2560, 3072};
  const int ns = (chain == 3) ? 3 : 2;

  // softmax of this chain's rc group
  if (tid < 16) {
    int row = tid;
    int goff = (chain == 3) ? 6 : chain * 2;
    float v[3], mx = -1e30f;
    for (int j = 0; j < ns; ++j) { v[j] = rcs[(b0 + row) * 16 + goff + j]; mx = fmaxf(mx, v[j]); }
    float s = 0.f;
    for (int j = 0; j < ns; ++j) { v[j] = __expf(v[j] - mx); s += v[j]; }
    float inv = 1.0f / s;
    for (int j = 0; j < ns; ++j) rcl[row][j] = v[j] * inv;
  }
  for (int i = tid; i < 2 * 16 * 136; i += 512) {
    (&hhi[0][0][0])[i] = (bf16)0.0f;
    (&hlo[0][0][0])[i] = (bf16)0.0f;
  }

  const bf16* WhhH = hiAll + WhhOff[chain];
  const bf16* WhhL = loAll + WhhOff[chain];
  bf16x8 whf[4][4], whl[4][4];
#pragma unroll
  for (int g = 0; g < 4; ++g)
#pragma unroll
    for (int ks = 0; ks < 4; ++ks) {
      int o = (g * 128 + u) * 128 + ks * 32 + q * 8;
      whf[g][ks] = *(const bf16x8*)(WhhH + o);
      whl[g][ks] = *(const bf16x8*)(WhhL + o);
    }
  const bf16* WihH = hiAll + WihOff[chain];
  const bf16* WihL = loAll + WihOff[chain];
  const float* bias = fmisc + bOff[chain];
  float bg[4];
#pragma unroll
  for (int g = 0; g < 4; ++g) bg[g] = bias[g * 128 + u];

  const int preMk0[4] = {0, 1, 5, 2};
  const int preMk1[4] = {4, 8, 9, 6};
  float creg[4] = {0.f, 0.f, 0.f, 0.f};
  __syncthreads();

  for (int s = 0; s < ns; ++s) {
    int p = s & 1;
    int mk = (s == 0) ? preMk0[chain] : (s == 1 ? preMk1[chain] : 10);
    // build x into buffer p
#pragma unroll
    for (int rr = 0; rr < 4; ++rr) {
      int row = rgg * 4 + rr;
      float pv = usc[(mk * 1024 + b0 + row) * 128 + u2];
      float xv = rcl[row][s] * pv;
      bf16 xh = (bf16)xv;
      xhi[p][row][u2] = xh;
      xlo[p][row][u2] = (bf16)(xv - (float)xh);
    }
    __syncthreads();
    f32x4 acc[4];
    const f32x4 zf = {0.f, 0.f, 0.f, 0.f};
#pragma unroll
    for (int g = 0; g < 4; ++g) acc[g] = zf;
    lstm_step_mfma(acc, xhi, xlo, hhi, hlo, p, WihH, WihL, whf, whl, n16, q, u);
#pragma unroll
    for (int e = 0; e < 4; ++e) {
      int row = q * 4 + e;
      float gi = acc[0][e] + bg[0];
      float gf = acc[1][e] + bg[1];
      float gg = acc[2][e] + bg[2];
      float go = acc[3][e] + bg[3];
      float c = sigm(gf) * creg[e] + sigm(gi) * tanh_f(gg);
      creg[e] = c;
      float h = sigm(go) * tanh_f(c);
      bf16 hh = (bf16)h;
      hhi[p ^ 1][row][u] = hh;
      hlo[p ^ 1][row][u] = (bf16)(h - (float)hh);
      if (s == ns - 1) bcg[(chain * 1024 + b0 + row) * 128 + u] = h;
    }
  }
}

__global__ __launch_bounds__(512) void decision(const float* __restrict__ usc,
                                                const float* __restrict__ rcs,
                                                const bf16* __restrict__ hiAll,
                                                const bf16* __restrict__ loAll,
                                                const float* __restrict__ fmisc,
                                                const float* __restrict__ bcg,
                                                float* __restrict__ dcF,
                                                float* __restrict__ dcB) {
  __shared__ __align__(16) bf16 xhi[2][16][136], xlo[2][16][136], hhi[2][16][136], hlo[2][16][136];
  __shared__ float rcl[16][7];
  LSTM_STEP_DECL
  const int dir = blockIdx.y;
  const int b0 = blockIdx.x * 16;

  if (tid < 16) {
    int row = tid;
    float v[7], mx = -1e30f;
    for (int j = 0; j < 7; ++j) { v[j] = rcs[(b0 + row) * 16 + 9 + j]; mx = fmaxf(mx, v[j]); }
    float s = 0.f;
    for (int j = 0; j < 7; ++j) { v[j] = __expf(v[j] - mx); s += v[j]; }
    float inv = 1.0f / s;
    for (int j = 0; j < 7; ++j) rcl[row][j] = v[j] * inv;
  }
  for (int i = tid; i < 2 * 16 * 136; i += 512) {
    (&hhi[0][0][0])[i] = (bf16)0.0f;
    (&hlo[0][0][0])[i] = (bf16)0.0f;
  }

  const int WihOffD[2] = {868352, 999424};
  const int WhhOffD[2] = {933888, 1064960};
  const int bOffD[2] = {3584, 4096};
  const bf16* WhhH = hiAll + WhhOffD[dir];
  const bf16* WhhL = loAll + WhhOffD[dir];
  bf16x8 whf[4][4], whl[4][4];
#pragma unroll
  for (int g = 0; g < 4; ++g)
#pragma unroll
    for (int ks = 0; ks < 4; ++ks) {
      int o = (g * 128 + u) * 128 + ks * 32 + q * 8;
      whf[g][ks] = *(const bf16x8*)(WhhH + o);
      whl[g][ks] = *(const bf16x8*)(WhhL + o);
    }
  const bf16* WihH = hiAll + WihOffD[dir];
  const bf16* WihL = loAll + WihOffD[dir];
  const float* bias = fmisc + bOffD[dir];
  float bg[4];
#pragma unroll
  for (int g = 0; g < 4; ++g) bg[g] = bias[g * 128 + u];

  const int dmk[3] = {3, 7, 11};
  float creg[4] = {0.f, 0.f, 0.f, 0.f};
  __syncthreads();

  for (int s = 0; s < 7; ++s) {
    int p = s & 1;
    int j = dir ? (6 - s) : s;
#pragma unroll
    for (int rr = 0; rr < 4; ++rr) {
      int row = rgg * 4 + rr;
      float pv = (j < 3) ? usc[(dmk[j] * 1024 + b0 + row) * 128 + u2]
                         : bcg[((j - 3) * 1024 + b0 + row) * 128 + u2];
      float xv = rcl[row][j] * pv;
      bf16 xh = (bf16)xv;
      xhi[p][row][u2] = xh;
      xlo[p][row][u2] = (bf16)(xv - (float)xh);
    }
    __syncthreads();
    f32x4 acc[4];
    const f32x4 zf = {0.f, 0.f, 0.f, 0.f};
#pragma unroll
    for (int g = 0; g < 4; ++g) acc[g] = zf;
    lstm_step_mfma(acc, xhi, xlo, hhi, hlo, p, WihH, WihL, whf, whl, n16, q, u);
#pragma unroll
    for (int e = 0; e < 4; ++e) {
      int row = q * 4 + e;
      float gi = acc[0][e] + bg[0];
      float gf = acc[1][e] + bg[1];
      float gg = acc[2][e] + bg[2];
      float go = acc[3][e] + bg[3];
      float c = sigm(gf) * creg[e] + sigm(gi) * tanh_f(gg);
      creg[e] = c;
      float h = sigm(go) * tanh_f(c);
      bf16 hh = (bf16)h;
      hhi[p ^ 1][row][u] = hh;
      hlo[p ^ 1][row][u] = (bf16)(h - (float)hh);
      if (s == 6) {
        if (dir == 0) dcF[(b0 + row) * 128 + u] = h;
        else dcB[(b0 + row) * 128 + u] = h;
      }
    }
  }
}

__global__ __launch_bounds__(256) void rupdate(const float* __restrict__ usc,
                                               const float* __restrict__ bcg,
                                               const float* __restrict__ dcF,
                                               const float* __restrict__ dcB,
                                               float* __restrict__ rcs,
                                               float* __restrict__ dcw, int last) {
  __shared__ float dsum[16][128];
  __shared__ float rcl[16][16];
  const int tid = threadIdx.x;
  const int b0 = blockIdx.x * 16;
  for (int i = tid; i < 2048; i += 256) {
    int row = i >> 7, col = i & 127;
    float v = dcF[(b0 + row) * 128 + col] + dcB[(b0 + row) * 128 + col];
    dsum[row][col] = v;
    if (last) dcw[(b0 + row) * 128 + col] = v;
  }
  {
    int row = tid >> 4, cap = tid & 15;
    rcl[row][cap] = rcs[(b0 + row) * 16 + cap];
  }
  __syncthreads();
  if (!last) {
    int row = tid >> 4, cap = tid & 15;
    const int goffT[16] = {0, 0, 2, 2, 4, 4, 6, 6, 6, 9, 9, 9, 9, 9, 9, 9};
    const int gnT[16] = {2, 2, 2, 2, 2, 2, 3, 3, 3, 7, 7, 7, 7, 7, 7, 7};
    int go = goffT[cap], gn = gnT[cap];
    float mx = -1e30f;
    for (int j = 0; j < gn; ++j) mx = fmaxf(mx, rcl[row][go + j]);
    float s = 0.f;
    for (int j = 0; j < gn; ++j) s += __expf(rcl[row][go + j] - mx);
    float sm = __expf(rcl[row][cap] - mx) / s;

    const int preMkTab[9] = {0, 4, 1, 8, 5, 9, 2, 6, 10};
    float a = 0.f;
    if (cap < 9) {
      int i = (cap < 6) ? (cap >> 1) : 3;
      const float* pr = usc + (preMkTab[cap] * 1024 + b0 + row) * 128;
      const float* bcrow = bcg + (i * 1024 + b0 + row) * 128;
      for (int dd = 0; dd < 128; ++dd) a += pr[dd] * bcrow[dd];
    } else {
      int j = cap - 9;
      if (j < 3) {
        const int dmk[3] = {3, 7, 11};
        const float* pr = usc + (dmk[j] * 1024 + b0 + row) * 128;
        for (int dd = 0; dd < 128; ++dd) a += pr[dd] * dsum[row][dd];
      } else {
        const float* bcrow = bcg + ((j - 3) * 1024 + b0 + row) * 128;
        for (int dd = 0; dd < 128; ++dd) a += bcrow[dd] * dsum[row][dd];
      }
    }
    rcs[(b0 + row) * 16 + cap] = sm + a;
  }
}

// ---------------- head ----------------
__global__ __launch_bounds__(64) void head(const float* __restrict__ dc, const float* __restrict__ fcw,
                                           void* __restrict__ out, const int* __restrict__ flag) {
  int b = blockIdx.x, j = threadIdx.x;
  const float* r = dc + b * 128;
  float acc = fcw[209408 + j];
  for (int dd = 0; dd < 128; ++dd) acc += r[dd] * fcw[201216 + j * 128 + dd];
  float o = tanh_f(acc) * fcw[209472 + j];
  for (int off = 32; off; off >>= 1) o += __shfl_down(o, off, 64);
  if (j == 0) {
    float res = o + fcw[209536];
    if (*flag) ((float*)out)[b] = res;
    else ((bf16*)out)[b] = (bf16)res;
  }
}

extern "C" void kernel_launch(void* const* d_in, const int* in_sizes, int n_in,
                              void* d_out, int out_size, void* d_ws, size_t ws_size,
                              hipStream_t stream) {
  float* fw = (float*)d_ws;
  int* flag = (int*)d_ws;
  float* ctx = fw + 4;                  // 393216
  float* usc = ctx + 393216;            // 1572864
  float* dcw = usc + 1572864;           // 131072
  float* fmisc = dcw + 131072;          // 209552
  float* rcs = fmisc + 209552;          // 16384
  float* bcg = rcs + 16384;             // 524288
  float* dcF = bcg + 524288;            // 131072
  float* dcB = dcF + 131072;            // 131072
  bf16* hiAll = (bf16*)(dcB + 131072);  // 1130496 el
  bf16* loAll = hiAll + 1130496;

  hipLaunchKernelGGL(detect_dtype, dim3(1), dim3(256), 0, stream,
                     (const unsigned short*)d_in[0], flag);

  PadArgs pa;
  HiloArgs ha;
  for (int m = 0; m < 3; ++m)
    for (int dd = 0; dd < 2; ++dd) {
      int md = m * 6 + dd * 3;
      pa.src[m * 2 + dd] = d_in[3 + md + 0];
      ha.src[m * 2 + dd] = d_in[3 + md + 1];
      ha.n[m * 2 + dd] = 16384;
      ha.off[m * 2 + dd] = 245760 + (m * 2 + dd) * 16384;
    }
  const int hsrc[6] = {24, 25, 27, 28, 30, 31};
  const int hn[6] = {262144, 262144, 65536, 65536, 65536, 65536};
  const int hoff[6] = {344064, 606208, 868352, 933888, 999424, 1064960};
  for (int j = 0; j < 6; ++j) { ha.src[6 + j] = d_in[hsrc[j]]; ha.n[6 + j] = hn[j]; ha.off[6 + j] = hoff[j]; }
  hipLaunchKernelGGL(conv_pad, dim3(64, 6), dim3(256), 0, stream, pa, hiAll, loAll, (const int*)flag);
  hipLaunchKernelGGL(conv_hilo, dim3(128, 12), dim3(256), 0, stream, ha, hiAll, loAll, (const int*)flag);

  F32Args fa;
  for (int m = 0; m < 3; ++m)
    for (int dd = 0; dd < 2; ++dd) {
      fa.src[m * 2 + dd] = d_in[3 + m * 6 + dd * 3 + 2];
      fa.n[m * 2 + dd] = 256;
      fa.off[m * 2 + dd] = (m * 2 + dd) * 256;
    }
  const int fsrc[10] = {26, 29, 32, 21, 22, 23, 33, 34, 35, 36};
  const int fn[10] = {2048, 512, 512, 65536, 65536, 65536, 8192, 64, 64, 1};
  const int foff[10] = {1536, 3584, 4096, 4608, 70144, 135680, 201216, 209408, 209472, 209536};
  for (int j = 0; j < 10; ++j) { fa.src[6 + j] = d_in[fsrc[j]]; fa.n[6 + j] = fn[j]; fa.off[6 + j] = foff[j]; }
  hipLaunchKernelGGL(conv_f32, dim3(64, 16), dim3(256), 0, stream, fa, fmisc, (const int*)flag);
  hipLaunchKernelGGL(init_rc, dim3(64), dim3(256), 0, stream, rcs);

  TriArgs ta;
  ta.x[0] = d_in[0]; ta.x[1] = d_in[1]; ta.x[2] = d_in[2];
  ta.hiAll = hiAll; ta.loAll = loAll; ta.fmisc = fmisc; ta.ctx = ctx; ta.flag = flag;
  hipLaunchKernelGGL(tri_lstm, dim3(384), dim3(256), 0, stream, ta);

  hipLaunchKernelGGL(usc_kern, dim3(256, 12), dim3(128), 0, stream,
                     (const float*)ctx, (const float*)fmisc, usc);

  for (int r = 0; r < 4; ++r) {
    hipLaunchKernelGGL(rchain, dim3(64, 4), dim3(512), 0, stream,
                       (const float*)usc, (const float*)rcs, (const bf16*)hiAll,
                       (const bf16*)loAll, (const float*)fmisc, bcg);
    hipLaunchKernelGGL(decision, dim3(64, 2), dim3(512), 0, stream,
                       (const float*)usc, (const float*)rcs, (const bf16*)hiAll,
                       (const bf16*)loAll, (const float*)fmisc, (const float*)bcg, dcF, dcB);
    hipLaunchKernelGGL(rupdate, dim3(64), dim3(256), 0, stream,
                       (const float*)usc, (const float*)bcg, (const float*)dcF,
                       (const float*)dcB, rcs, dcw, (r == 3) ? 1 : 0);
  }

  hipLaunchKernelGGL(head, dim3(1024), dim3(64), 0, stream,
                     (const float*)dcw, (const float*)fmisc, d_out, (const int*)flag);
}

// Round 4
// 906.828 us; speedup vs baseline: 4.2053x; 1.7732x over previous
//
#include <hip/hip_runtime.h>

typedef __bf16 bf16;
typedef _Float16 f16;
typedef f16 f16x8 __attribute__((ext_vector_type(8)));
typedef float f32x4 __attribute__((ext_vector_type(4)));

__device__ __forceinline__ f32x4 mfma16h(f16x8 a, f16x8 b, f32x4 c) {
  return __builtin_amdgcn_mfma_f32_16x16x32_f16(a, b, c, 0, 0, 0);
}
__device__ __forceinline__ float sigm(float x) { return 1.0f / (1.0f + __expf(-x)); }
__device__ __forceinline__ float tanh_f(float x) {
  float e = __expf(-2.0f * fabsf(x));
  return copysignf((1.0f - e) / (1.0f + e), x);
}
__device__ __forceinline__ float ldin(const void* p, long i, int f32m) {
  if (f32m) return ((const float*)p)[i];
  unsigned u = (unsigned)((const unsigned short*)p)[i] << 16;
  return __uint_as_float(u);
}
__device__ __forceinline__ unsigned short f16u(f16 h) { return __builtin_bit_cast(unsigned short, h); }
__device__ __forceinline__ float bfc(unsigned short s) { return __uint_as_float((unsigned)s << 16); }

// ---------------- dtype detection ----------------
__global__ void detect_dtype(const unsigned short* __restrict__ p, int* __restrict__ flag) {
  __shared__ int cnt;
  if (threadIdx.x == 0) cnt = 0;
  __syncthreads();
  int c = 0;
  for (int i = threadIdx.x; i < 4096; i += 256) {
    unsigned e = (p[2 * i] >> 7) & 0xFFu;
    if (e >= 0xC0u) ++c;
  }
  atomicAdd(&cnt, c);
  __syncthreads();
  if (threadIdx.x == 0) *flag = (cnt > 64) ? 1 : 0;
}

// ---------------- converters: all weights -> single fp16 ----------------
// wAll (f16) element offsets:
//   padded tri Wih: table below                    total 245760
//   tri Whh: 245760 + md*16384                     total 98304
//   r_Wih: 344064 + c*65536   r_Whh: 606208 + c*65536
//   dWihF: 868352  dWhhF: 933888  dWihB: 999424  dWhhB: 1064960   end 1130496
// fmisc float offsets: tri bias md*256; r_b 1536; d_b_f 3584; d_b_b 4096;
//   uscW 4608+mk*16384; fc1W 201216; fc1b 209408; fc2W 209472; fc2b 209536

struct PadArgs { const void* src[6]; };
__global__ void conv_pad(PadArgs a, f16* __restrict__ wo, const int* __restrict__ flag) {
  const int dinT[6] = {300, 300, 74, 74, 35, 35};
  const int kpT[6] = {320, 320, 96, 96, 64, 64};
  const int offT[6] = {0, 81920, 163840, 188416, 212992, 229376};
  int id = blockIdx.y;
  int din = dinT[id], kp = kpT[id];
  const void* s = a.src[id];
  f16* o = wo + offT[id];
  int f32m = *flag;
  int total = 256 * kp;
  for (int i = blockIdx.x * blockDim.x + threadIdx.x; i < total; i += gridDim.x * blockDim.x) {
    int n = i / kp, k = i - n * kp;
    float v = (k < din) ? ldin(s, n * din + k, f32m) : 0.0f;
    o[i] = (f16)v;
  }
}

struct HiloArgs { const void* src[12]; int n[12]; int off[12]; };
__global__ void conv_h16(HiloArgs a, f16* __restrict__ wo, const int* __restrict__ flag) {
  int j = blockIdx.y;
  int n = a.n[j];
  const void* s = a.src[j];
  f16* o = wo + a.off[j];
  int f32m = *flag;
  for (int i = blockIdx.x * blockDim.x + threadIdx.x; i < n; i += gridDim.x * blockDim.x)
    o[i] = (f16)ldin(s, i, f32m);
}

struct F32Args { const void* src[16]; int n[16]; int off[16]; };
__global__ void conv_f32(F32Args a, float* __restrict__ dst, const int* __restrict__ flag) {
  int j = blockIdx.y;
  int n = a.n[j];
  const void* s = a.src[j];
  float* d = dst + a.off[j];
  int f32m = *flag;
  for (int i = blockIdx.x * blockDim.x + threadIdx.x; i < n; i += gridDim.x * blockDim.x)
    d[i] = ldin(s, i, f32m);
}

__global__ void init_rc(float* __restrict__ rcs) {
  int i = blockIdx.x * 256 + threadIdx.x;
  if (i < 16384) rcs[i] = 1.0f;
}

// ---------------- fused trimodal bidirectional LSTMs (fp16 MFMA) ----------------
struct TriArgs {
  const void* x[3];
  const f16* wAll;
  const float* fmisc;
  float* ctx;
  const int* flag;
};

// wave w owns gate-slice u = w*16+n16; gate g output rows g*64+u.
// x-proj: 2 terms (xhi,xlo f16 x single-f16 W); recurrence: 1 term (f16 h).
template <int DIN, int KP, int CHUNK, int F32M>
__device__ void tri_body(const void* __restrict__ xsrc,
                         const f16* __restrict__ wp, const f16* __restrict__ whh,
                         const float* __restrict__ bias, float* __restrict__ ctx,
                         int m, int d, int b0, char* sm) {
  constexpr int XP = KP + 8;
  constexpr int NKS = KP / 32;
  constexpr int NCH = DIN / CHUNK;     // 75 / 37 / 35 (exact)
  constexpr int ITER = (NCH + 7) / 8;  // 10 / 5 / 5

  f16 (*Xhi)[XP] = (f16 (*)[XP])sm;
  f16 (*Xlo)[XP] = (f16 (*)[XP])(sm + 32 * XP * 2);
  f16 (*hbuf)[16][72] = (f16 (*)[16][72])(sm + 64 * XP * 2);

  const int tid = threadIdx.x;
  const int lane = tid & 63, n16 = lane & 15, q = lane >> 4, w = tid >> 6;
  const int u = w * 16 + n16;
  const int srow = tid & 31, sct = tid >> 5;  // staging: row, chunk-lane

  {  // zero X pads + h buffers
    unsigned* z = (unsigned*)sm;
    int nz = (64 * XP * 2 + 4608) >> 2;
    for (int i = tid; i < nz; i += 256) z[i] = 0u;
  }

  // Whh^T fragments (single f16), constant over time: 8 frags = 32 VGPR
  f16x8 wf[4][2];
#pragma unroll
  for (int g = 0; g < 4; ++g)
#pragma unroll
    for (int ks = 0; ks < 2; ++ks)
      wf[g][ks] = *(const f16x8*)(whh + (g * 64 + u) * 64 + ks * 32 + q * 8);
  float bg[4];
#pragma unroll
  for (int g = 0; g < 4; ++g) bg[g] = bias[g * 64 + u];

  uint4 pf[ITER];
  auto stage_load = [&](int tg) {
#pragma unroll
    for (int i = 0; i < ITER; ++i) {
      int c = sct + i * 8;
      if (c < NCH) {
        int tl = srow >> 4, bb = srow & 15;
        int t = tg * 2 + tl; if (d) t = 127 - t;
        long base = ((long)(b0 + bb) * 128 + t) * DIN + c * CHUNK;
        if (F32M) {
          const float* p = (const float*)xsrc + base;
          if constexpr (CHUNK == 4) pf[i] = *(const uint4*)p;
          else if constexpr (CHUNK == 2) { uint2 v = *(const uint2*)p; pf[i].x = v.x; pf[i].y = v.y; }
          else pf[i].x = *(const unsigned*)p;
        } else {
          const unsigned short* p = (const unsigned short*)xsrc + base;
          if constexpr (CHUNK == 4) { uint2 v = *(const uint2*)p; pf[i].x = v.x; pf[i].y = v.y; }
          else if constexpr (CHUNK == 2) pf[i].x = *(const unsigned*)p;
          else pf[i].x = *p;
        }
      }
    }
  };
  auto stage_store = [&]() {
#pragma unroll
    for (int i = 0; i < ITER; ++i) {
      int c = sct + i * 8;
      if (c < NCH) {
        float v[4];
        if (F32M) {
          v[0] = __uint_as_float(pf[i].x); v[1] = __uint_as_float(pf[i].y);
          v[2] = __uint_as_float(pf[i].z); v[3] = __uint_as_float(pf[i].w);
        } else {
          v[0] = bfc((unsigned short)(pf[i].x & 0xFFFF));
          v[1] = bfc((unsigned short)(pf[i].x >> 16));
          v[2] = bfc((unsigned short)(pf[i].y & 0xFFFF));
          v[3] = bfc((unsigned short)(pf[i].y >> 16));
        }
        unsigned short hb[4], lb[4];
#pragma unroll
        for (int e = 0; e < CHUNK; ++e) {
          f16 h = (f16)v[e];
          hb[e] = f16u(h);
          lb[e] = f16u((f16)(v[e] - (float)h));
        }
        if constexpr (CHUNK == 4) {
          uint2 H; H.x = hb[0] | ((unsigned)hb[1] << 16); H.y = hb[2] | ((unsigned)hb[3] << 16);
          *(uint2*)&Xhi[srow][c * 4] = H;
          if (F32M) {
            uint2 L; L.x = lb[0] | ((unsigned)lb[1] << 16); L.y = lb[2] | ((unsigned)lb[3] << 16);
            *(uint2*)&Xlo[srow][c * 4] = L;
          }
        } else if constexpr (CHUNK == 2) {
          *(unsigned*)&Xhi[srow][c * 2] = hb[0] | ((unsigned)hb[1] << 16);
          if (F32M) *(unsigned*)&Xlo[srow][c * 2] = lb[0] | ((unsigned)lb[1] << 16);
        } else {
          *(unsigned short*)&Xhi[srow][c] = hb[0];
          if (F32M) *(unsigned short*)&Xlo[srow][c] = lb[0];
        }
      }
    }
  };

  float c4[4] = {0.f, 0.f, 0.f, 0.f};
  int par = 0;
  stage_load(0);
  __syncthreads();  // zero-init visible

  for (int tg = 0; tg < 64; ++tg) {
    stage_store();
    if (tg < 63) stage_load(tg + 1);
    __syncthreads();

    f32x4 acc[2][4];
    const f32x4 zf = {0.f, 0.f, 0.f, 0.f};
#pragma unroll
    for (int rt = 0; rt < 2; ++rt)
#pragma unroll
      for (int g = 0; g < 4; ++g) acc[rt][g] = zf;

#pragma unroll
    for (int ks = 0; ks < NKS; ++ks) {
      f16x8 ah0 = *(const f16x8*)(&Xhi[n16][ks * 32 + q * 8]);
      f16x8 ah1 = *(const f16x8*)(&Xhi[16 + n16][ks * 32 + q * 8]);
      f16x8 al0, al1;
      if (F32M) {
        al0 = *(const f16x8*)(&Xlo[n16][ks * 32 + q * 8]);
        al1 = *(const f16x8*)(&Xlo[16 + n16][ks * 32 + q * 8]);
      }
#pragma unroll
      for (int g = 0; g < 4; ++g) {
        f16x8 bh = *(const f16x8*)(wp + (g * 64 + u) * KP + ks * 32 + q * 8);
        acc[0][g] = mfma16h(ah0, bh, acc[0][g]);
        acc[1][g] = mfma16h(ah1, bh, acc[1][g]);
        if (F32M) {
          acc[0][g] = mfma16h(al0, bh, acc[0][g]);
          acc[1][g] = mfma16h(al1, bh, acc[1][g]);
        }
      }
    }

#pragma unroll
    for (int tl = 0; tl < 2; ++tl) {
#pragma unroll
      for (int ks = 0; ks < 2; ++ks) {
        f16x8 ah = *(const f16x8*)(&hbuf[par][n16][ks * 32 + q * 8]);
#pragma unroll
        for (int g = 0; g < 4; ++g) acc[tl][g] = mfma16h(ah, wf[g][ks], acc[tl][g]);
      }
      const bool lastStep = (tg == 63) && (tl == 1);
#pragma unroll
      for (int e = 0; e < 4; ++e) {
        int row = q * 4 + e;
        float gi = acc[tl][0][e] + bg[0];
        float gf = acc[tl][1][e] + bg[1];
        float gg = acc[tl][2][e] + bg[2];
        float go = acc[tl][3][e] + bg[3];
        float c = sigm(gf) * c4[e] + sigm(gi) * tanh_f(gg);
        c4[e] = c;
        float h = sigm(go) * tanh_f(c);
        hbuf[par ^ 1][row][u] = (f16)h;
        if (lastStep) ctx[(m * 1024 + b0 + row) * 128 + d * 64 + u] = h;
      }
      par ^= 1;
      __syncthreads();
    }
  }
}

__global__ __launch_bounds__(256) void tri_lstm(TriArgs A) {
  __shared__ __align__(16) char sm[64 * 328 * 2 + 4608];
  int bid = blockIdx.x;
  int md = bid >> 6, xb = bid & 63;
  int m = md >> 1, d = md & 1, b0 = xb * 16;
  const int wpOffT[6] = {0, 81920, 163840, 188416, 212992, 229376};
  const f16* wp = A.wAll + wpOffT[md];
  const f16* whh = A.wAll + 245760 + md * 16384;
  const float* bias = A.fmisc + md * 256;
  int f32m = *A.flag;
  if (f32m) {
    if (m == 0)      tri_body<300, 320, 4, 1>(A.x[0], wp, whh, bias, A.ctx, m, d, b0, sm);
    else if (m == 1) tri_body<74, 96, 2, 1>(A.x[1], wp, whh, bias, A.ctx, m, d, b0, sm);
    else             tri_body<35, 64, 1, 1>(A.x[2], wp, whh, bias, A.ctx, m, d, b0, sm);
  } else {
    if (m == 0)      tri_body<300, 320, 4, 0>(A.x[0], wp, whh, bias, A.ctx, m, d, b0, sm);
    else if (m == 1) tri_body<74, 96, 2, 0>(A.x[1], wp, whh, bias, A.ctx, m, d, b0, sm);
    else             tri_body<35, 64, 1, 0>(A.x[2], wp, whh, bias, A.ctx, m, d, b0, sm);
  }
}

// ---------------- usc einsum (4 rows/block for W reuse) ----------------
__global__ __launch_bounds__(128) void usc_kern(const float* __restrict__ ctx,
                                                const float* __restrict__ fmisc,
                                                float* __restrict__ usc) {
  __shared__ float cr[4][128];
  int b0 = blockIdx.x * 4;
  int mk = blockIdx.y, mod = mk >> 2;
  int e = threadIdx.x;
  const float* W = fmisc + 4608 + mk * 16384;
  for (int i = e; i < 512; i += 128) {
    int r = i >> 7, dd = i & 127;
    cr[r][dd] = ctx[(mod * 1024 + b0 + r) * 128 + dd];
  }
  __syncthreads();
  float a0 = 0.f, a1 = 0.f, a2 = 0.f, a3 = 0.f;
  for (int dd = 0; dd < 128; ++dd) {
    float wv = W[dd * 128 + e];
    a0 += cr[0][dd] * wv; a1 += cr[1][dd] * wv;
    a2 += cr[2][dd] * wv; a3 += cr[3][dd] * wv;
  }
  usc[(mk * 1024 + b0 + 0) * 128 + e] = a0;
  usc[(mk * 1024 + b0 + 1) * 128 + e] = a1;
  usc[(mk * 1024 + b0 + 2) * 128 + e] = a2;
  usc[(mk * 1024 + b0 + 3) * 128 + e] = a3;
}

// ---------------- routing phase kernels (fp16 MFMA) ----------------
#define LSTM_STEP_DECL \
  const int tid = threadIdx.x; \
  const int lane = tid & 63, n16 = lane & 15, q = lane >> 4, w = tid >> 6; \
  const int u = w * 16 + n16; \
  const int u2 = tid & 127, rgg = tid >> 7;

__device__ __forceinline__ void lstm_step_mfma(
    f32x4* acc, const f16 (*xh)[16][136], const f16 (*xl)[16][136],
    const f16 (*hh)[16][136], int p,
    const f16* __restrict__ Wih, const f16x8 (*whf)[4],
    int n16, int q, int u) {
#pragma unroll
  for (int ks = 0; ks < 4; ++ks) {
    f16x8 axh = *(const f16x8*)(&xh[p][n16][ks * 32 + q * 8]);
    f16x8 axl = *(const f16x8*)(&xl[p][n16][ks * 32 + q * 8]);
    f16x8 ahh = *(const f16x8*)(&hh[p][n16][ks * 32 + q * 8]);
#pragma unroll
    for (int g = 0; g < 4; ++g) {
      f16x8 bh = *(const f16x8*)(Wih + (g * 128 + u) * 128 + ks * 32 + q * 8);
      acc[g] = mfma16h(axh, bh, acc[g]);
      acc[g] = mfma16h(axl, bh, acc[g]);
      acc[g] = mfma16h(ahh, whf[g][ks], acc[g]);
    }
  }
}

__global__ __launch_bounds__(512) void rchain(const float* __restrict__ usc,
                                              const float* __restrict__ rcs,
                                              const f16* __restrict__ wAll,
                                              const float* __restrict__ fmisc,
                                              float* __restrict__ bcg) {
  __shared__ __align__(16) f16 xh[2][16][136], xl[2][16][136], hh[2][16][136];
  __shared__ float rcl[16][3];
  LSTM_STEP_DECL
  const int chain = blockIdx.y;
  const int b0 = blockIdx.x * 16;
  const int WihOff[4] = {344064, 409600, 475136, 540672};
  const int WhhOff[4] = {606208, 671744, 737280, 802816};
  const int bOff[4] = {1536, 2048, 2560, 3072};
  const int ns = (chain == 3) ? 3 : 2;

  if (tid < 16) {
    int row = tid;
    int goff = (chain == 3) ? 6 : chain * 2;
    float v[3], mx = -1e30f;
    for (int j = 0; j < ns; ++j) { v[j] = rcs[(b0 + row) * 16 + goff + j]; mx = fmaxf(mx, v[j]); }
    float s = 0.f;
    for (int j = 0; j < ns; ++j) { v[j] = __expf(v[j] - mx); s += v[j]; }
    float inv = 1.0f / s;
    for (int j = 0; j < ns; ++j) rcl[row][j] = v[j] * inv;
  }
  for (int i = tid; i < 2 * 16 * 136; i += 512) (&hh[0][0][0])[i] = (f16)0.0f;

  const f16* Whh = wAll + WhhOff[chain];
  f16x8 whf[4][4];
#pragma unroll
  for (int g = 0; g < 4; ++g)
#pragma unroll
    for (int ks = 0; ks < 4; ++ks)
      whf[g][ks] = *(const f16x8*)(Whh + (g * 128 + u) * 128 + ks * 32 + q * 8);
  const f16* Wih = wAll + WihOff[chain];
  const float* bias = fmisc + bOff[chain];
  float bg[4];
#pragma unroll
  for (int g = 0; g < 4; ++g) bg[g] = bias[g * 128 + u];

  const int preMk0[4] = {0, 1, 5, 2};
  const int preMk1[4] = {4, 8, 9, 6};
  float creg[4] = {0.f, 0.f, 0.f, 0.f};
  __syncthreads();

  for (int s = 0; s < ns; ++s) {
    int p = s & 1;
    int mk = (s == 0) ? preMk0[chain] : (s == 1 ? preMk1[chain] : 10);
#pragma unroll
    for (int rr = 0; rr < 4; ++rr) {
      int row = rgg * 4 + rr;
      float pv = usc[(mk * 1024 + b0 + row) * 128 + u2];
      float xv = rcl[row][s] * pv;
      f16 xhv = (f16)xv;
      xh[p][row][u2] = xhv;
      xl[p][row][u2] = (f16)(xv - (float)xhv);
    }
    __syncthreads();
    f32x4 acc[4];
    const f32x4 zf = {0.f, 0.f, 0.f, 0.f};
#pragma unroll
    for (int g = 0; g < 4; ++g) acc[g] = zf;
    lstm_step_mfma(acc, xh, xl, hh, p, Wih, whf, n16, q, u);
#pragma unroll
    for (int e = 0; e < 4; ++e) {
      int row = q * 4 + e;
      float gi = acc[0][e] + bg[0];
      float gf = acc[1][e] + bg[1];
      float gg = acc[2][e] + bg[2];
      float go = acc[3][e] + bg[3];
      float c = sigm(gf) * creg[e] + sigm(gi) * tanh_f(gg);
      creg[e] = c;
      float h = sigm(go) * tanh_f(c);
      hh[p ^ 1][row][u] = (f16)h;
      if (s == ns - 1) bcg[(chain * 1024 + b0 + row) * 128 + u] = h;
    }
  }
}

__global__ __launch_bounds__(512) void decision(const float* __restrict__ usc,
                                                const float* __restrict__ rcs,
                                                const f16* __restrict__ wAll,
                                                const float* __restrict__ fmisc,
                                                const float* __restrict__ bcg,
                                                float* __restrict__ dcF,
                                                float* __restrict__ dcB) {
  __shared__ __align__(16) f16 xh[2][16][136], xl[2][16][136], hh[2][16][136];
  __shared__ float rcl[16][7];
  LSTM_STEP_DECL
  const int dir = blockIdx.y;
  const int b0 = blockIdx.x * 16;

  if (tid < 16) {
    int row = tid;
    float v[7], mx = -1e30f;
    for (int j = 0; j < 7; ++j) { v[j] = rcs[(b0 + row) * 16 + 9 + j]; mx = fmaxf(mx, v[j]); }
    float s = 0.f;
    for (int j = 0; j < 7; ++j) { v[j] = __expf(v[j] - mx); s += v[j]; }
    float inv = 1.0f / s;
    for (int j = 0; j < 7; ++j) rcl[row][j] = v[j] * inv;
  }
  for (int i = tid; i < 2 * 16 * 136; i += 512) (&hh[0][0][0])[i] = (f16)0.0f;

  const int WihOffD[2] = {868352, 999424};
  const int WhhOffD[2] = {933888, 1064960};
  const int bOffD[2] = {3584, 4096};
  const f16* Whh = wAll + WhhOffD[dir];
  f16x8 whf[4][4];
#pragma unroll
  for (int g = 0; g < 4; ++g)
#pragma unroll
    for (int ks = 0; ks < 4; ++ks)
      whf[g][ks] = *(const f16x8*)(Whh + (g * 128 + u) * 128 + ks * 32 + q * 8);
  const f16* Wih = wAll + WihOffD[dir];
  const float* bias = fmisc + bOffD[dir];
  float bg[4];
#pragma unroll
  for (int g = 0; g < 4; ++g) bg[g] = bias[g * 128 + u];

  const int dmk[3] = {3, 7, 11};
  float creg[4] = {0.f, 0.f, 0.f, 0.f};
  __syncthreads();

  for (int s = 0; s < 7; ++s) {
    int p = s & 1;
    int j = dir ? (6 - s) : s;
#pragma unroll
    for (int rr = 0; rr < 4; ++rr) {
      int row = rgg * 4 + rr;
      float pv = (j < 3) ? usc[(dmk[j] * 1024 + b0 + row) * 128 + u2]
                         : bcg[((j - 3) * 1024 + b0 + row) * 128 + u2];
      float xv = rcl[row][j] * pv;
      f16 xhv = (f16)xv;
      xh[p][row][u2] = xhv;
      xl[p][row][u2] = (f16)(xv - (float)xhv);
    }
    __syncthreads();
    f32x4 acc[4];
    const f32x4 zf = {0.f, 0.f, 0.f, 0.f};
#pragma unroll
    for (int g = 0; g < 4; ++g) acc[g] = zf;
    lstm_step_mfma(acc, xh, xl, hh, p, Wih, whf, n16, q, u);
#pragma unroll
    for (int e = 0; e < 4; ++e) {
      int row = q * 4 + e;
      float gi = acc[0][e] + bg[0];
      float gf = acc[1][e] + bg[1];
      float gg = acc[2][e] + bg[2];
      float go = acc[3][e] + bg[3];
      float c = sigm(gf) * creg[e] + sigm(gi) * tanh_f(gg);
      creg[e] = c;
      float h = sigm(go) * tanh_f(c);
      hh[p ^ 1][row][u] = (f16)h;
      if (s == 6) {
        if (dir == 0) dcF[(b0 + row) * 128 + u] = h;
        else dcB[(b0 + row) * 128 + u] = h;
      }
    }
  }
}

__global__ __launch_bounds__(256) void rupdate(const float* __restrict__ usc,
                                               const float* __restrict__ bcg,
                                               const float* __restrict__ dcF,
                                               const float* __restrict__ dcB,
                                               float* __restrict__ rcs,
                                               float* __restrict__ dcw, int last) {
  __shared__ float dsum[16][128];
  __shared__ float rcl[16][16];
  const int tid = threadIdx.x;
  const int b0 = blockIdx.x * 16;
  for (int i = tid; i < 2048; i += 256) {
    int row = i >> 7, col = i & 127;
    float v = dcF[(b0 + row) * 128 + col] + dcB[(b0 + row) * 128 + col];
    dsum[row][col] = v;
    if (last) dcw[(b0 + row) * 128 + col] = v;
  }
  {
    int row = tid >> 4, cap = tid & 15;
    rcl[row][cap] = rcs[(b0 + row) * 16 + cap];
  }
  __syncthreads();
  if (!last) {
    int row = tid >> 4, cap = tid & 15;
    const int goffT[16] = {0, 0, 2, 2, 4, 4, 6, 6, 6, 9, 9, 9, 9, 9, 9, 9};
    const int gnT[16] = {2, 2, 2, 2, 2, 2, 3, 3, 3, 7, 7, 7, 7, 7, 7, 7};
    int go = goffT[cap], gn = gnT[cap];
    float mx = -1e30f;
    for (int j = 0; j < gn; ++j) mx = fmaxf(mx, rcl[row][go + j]);
    float s = 0.f;
    for (int j = 0; j < gn; ++j) s += __expf(rcl[row][go + j] - mx);
    float sm = __expf(rcl[row][cap] - mx) / s;

    const int preMkTab[9] = {0, 4, 1, 8, 5, 9, 2, 6, 10};
    float a = 0.f;
    if (cap < 9) {
      int i = (cap < 6) ? (cap >> 1) : 3;
      const float* pr = usc + (preMkTab[cap] * 1024 + b0 + row) * 128;
      const float* bcrow = bcg + (i * 1024 + b0 + row) * 128;
      for (int dd = 0; dd < 128; ++dd) a += pr[dd] * bcrow[dd];
    } else {
      int j = cap - 9;
      if (j < 3) {
        const int dmk[3] = {3, 7, 11};
        const float* pr = usc + (dmk[j] * 1024 + b0 + row) * 128;
        for (int dd = 0; dd < 128; ++dd) a += pr[dd] * dsum[row][dd];
      } else {
        const float* bcrow = bcg + ((j - 3) * 1024 + b0 + row) * 128;
        for (int dd = 0; dd < 128; ++dd) a += bcrow[dd] * dsum[row][dd];
      }
    }
    rcs[(b0 + row) * 16 + cap] = sm + a;
  }
}

// ---------------- head ----------------
__global__ __launch_bounds__(64) void head(const float* __restrict__ dc, const float* __restrict__ fcw,
                                           void* __restrict__ out, const int* __restrict__ flag) {
  int b = blockIdx.x, j = threadIdx.x;
  const float* r = dc + b * 128;
  float acc = fcw[209408 + j];
  for (int dd = 0; dd < 128; ++dd) acc += r[dd] * fcw[201216 + j * 128 + dd];
  float o = tanh_f(acc) * fcw[209472 + j];
  for (int off = 32; off; off >>= 1) o += __shfl_down(o, off, 64);
  if (j == 0) {
    float res = o + fcw[209536];
    if (*flag) ((float*)out)[b] = res;
    else ((bf16*)out)[b] = (bf16)res;
  }
}

extern "C" void kernel_launch(void* const* d_in, const int* in_sizes, int n_in,
                              void* d_out, int out_size, void* d_ws, size_t ws_size,
                              hipStream_t stream) {
  float* fw = (float*)d_ws;
  int* flag = (int*)d_ws;
  float* ctx = fw + 4;                  // 393216
  float* usc = ctx + 393216;            // 1572864
  float* dcw = usc + 1572864;           // 131072
  float* fmisc = dcw + 131072;          // 209552
  float* rcs = fmisc + 209552;          // 16384
  float* bcg = rcs + 16384;             // 524288
  float* dcF = bcg + 524288;            // 131072
  float* dcB = dcF + 131072;            // 131072
  f16* wAll = (f16*)(dcB + 131072);     // 1130496 el

  hipLaunchKernelGGL(detect_dtype, dim3(1), dim3(256), 0, stream,
                     (const unsigned short*)d_in[0], flag);

  PadArgs pa;
  HiloArgs ha;
  for (int m = 0; m < 3; ++m)
    for (int dd = 0; dd < 2; ++dd) {
      int md = m * 6 + dd * 3;
      pa.src[m * 2 + dd] = d_in[3 + md + 0];
      ha.src[m * 2 + dd] = d_in[3 + md + 1];
      ha.n[m * 2 + dd] = 16384;
      ha.off[m * 2 + dd] = 245760 + (m * 2 + dd) * 16384;
    }
  const int hsrc[6] = {24, 25, 27, 28, 30, 31};
  const int hn[6] = {262144, 262144, 65536, 65536, 65536, 65536};
  const int hoff[6] = {344064, 606208, 868352, 933888, 999424, 1064960};
  for (int j = 0; j < 6; ++j) { ha.src[6 + j] = d_in[hsrc[j]]; ha.n[6 + j] = hn[j]; ha.off[6 + j] = hoff[j]; }
  hipLaunchKernelGGL(conv_pad, dim3(64, 6), dim3(256), 0, stream, pa, wAll, (const int*)flag);
  hipLaunchKernelGGL(conv_h16, dim3(128, 12), dim3(256), 0, stream, ha, wAll, (const int*)flag);

  F32Args fa;
  for (int m = 0; m < 3; ++m)
    for (int dd = 0; dd < 2; ++dd) {
      fa.src[m * 2 + dd] = d_in[3 + m * 6 + dd * 3 + 2];
      fa.n[m * 2 + dd] = 256;
      fa.off[m * 2 + dd] = (m * 2 + dd) * 256;
    }
  const int fsrc[10] = {26, 29, 32, 21, 22, 23, 33, 34, 35, 36};
  const int fn[10] = {2048, 512, 512, 65536, 65536, 65536, 8192, 64, 64, 1};
  const int foff[10] = {1536, 3584, 4096, 4608, 70144, 135680, 201216, 209408, 209472, 209536};
  for (int j = 0; j < 10; ++j) { fa.src[6 + j] = d_in[fsrc[j]]; fa.n[6 + j] = fn[j]; fa.off[6 + j] = foff[j]; }
  hipLaunchKernelGGL(conv_f32, dim3(64, 16), dim3(256), 0, stream, fa, fmisc, (const int*)flag);
  hipLaunchKernelGGL(init_rc, dim3(64), dim3(256), 0, stream, rcs);

  TriArgs ta;
  ta.x[0] = d_in[0]; ta.x[1] = d_in[1]; ta.x[2] = d_in[2];
  ta.wAll = wAll; ta.fmisc = fmisc; ta.ctx = ctx; ta.flag = flag;
  hipLaunchKernelGGL(tri_lstm, dim3(384), dim3(256), 0, stream, ta);

  hipLaunchKernelGGL(usc_kern, dim3(256, 12), dim3(128), 0, stream,
                     (const float*)ctx, (const float*)fmisc, usc);

  for (int r = 0; r < 4; ++r) {
    hipLaunchKernelGGL(rchain, dim3(64, 4), dim3(512), 0, stream,
                       (const float*)usc, (const float*)rcs, (const f16*)wAll,
                       (const float*)fmisc, bcg);
    hipLaunchKernelGGL(decision, dim3(64, 2), dim3(512), 0, stream,
                       (const float*)usc, (const float*)rcs, (const f16*)wAll,
                       (const float*)fmisc, (const float*)bcg, dcF, dcB);
    hipLaunchKernelGGL(rupdate, dim3(64), dim3(256), 0, stream,
                       (const float*)usc, (const float*)bcg, (const float*)dcF,
                       (const float*)dcB, rcs, dcw, (r == 3) ? 1 : 0);
  }

  hipLaunchKernelGGL(head, dim3(1024), dim3(64), 0, stream,
                     (const float*)dcw, (const float*)fmisc, d_out, (const int*)flag);
}